// Round 1
// baseline (105.933 us; speedup 1.0000x reference)
//
#include <hip/hip_runtime.h>

#define IW 512
#define IH 512
#define NPLANES 48            // 16 batch * 3 channels
#define BLOCK 256

__device__ __forceinline__ void sort3(float& a, float& b, float& c) {
    float t;
    t = fminf(a, b); b = fmaxf(a, b); a = t;
    t = fminf(b, c); c = fmaxf(b, c); b = t;
    t = fminf(a, b); b = fmaxf(a, b); a = t;
}
__device__ __forceinline__ float med3f(float a, float b, float c) {
    return __builtin_amdgcn_fmed3f(a, b, c);
}
__device__ __forceinline__ float max3f(float a, float b, float c) {
    return fmaxf(fmaxf(a, b), c);
}
__device__ __forceinline__ float min3f(float a, float b, float c) {
    return fminf(fminf(a, b), c);
}

__global__ __launch_bounds__(BLOCK) void median3x3_kernel(
    const float* __restrict__ x, float* __restrict__ out) {
    int id = blockIdx.x * BLOCK + threadIdx.x;
    // layout: 128 thread-groups of 4 pixels per row, 512 rows, 48 planes
    int xg = id & 127;          // which group of 4 in the row
    int x0 = xg << 2;           // first output column
    int y  = (id >> 7) & (IH - 1);
    int p  = id >> 16;          // plane index (512*128 = 65536 = 2^16)

    const float* plane = x + (size_t)p * IH * IW;

    // reflect-pad row/col indices (pad = 1)
    int ym = (y == 0)       ? 1      : y - 1;
    int yp = (y == IH - 1)  ? IH - 2 : y + 1;
    int xl = (x0 == 0)      ? 1      : x0 - 1;
    int xr = (x0 + 4 == IW) ? IW - 2 : x0 + 4;

    // col[c][r]: 6 columns (x0-1 .. x0+4) x 3 rows
    float col[6][3];
    int rows[3] = {ym, y, yp};
#pragma unroll
    for (int i = 0; i < 3; i++) {
        const float* r = plane + (size_t)rows[i] * IW;
        float4 v = *(const float4*)(r + x0);
        col[0][i] = r[xl];
        col[1][i] = v.x;
        col[2][i] = v.y;
        col[3][i] = v.z;
        col[4][i] = v.w;
        col[5][i] = r[xr];
    }

    // vertical sort of each column -> lo/mid/hi
    float lo[6], mi[6], hi[6];
#pragma unroll
    for (int c = 0; c < 6; c++) {
        float a = col[c][0], b = col[c][1], d = col[c][2];
        sort3(a, b, d);
        lo[c] = a; mi[c] = b; hi[c] = d;
    }

    // median of 9 = med3( max3(lo), med3(mi), min3(hi) ) over 3 adjacent cols
    float o[4];
#pragma unroll
    for (int j = 0; j < 4; j++) {
        float M = max3f(lo[j], lo[j + 1], lo[j + 2]);
        float m = med3f(mi[j], mi[j + 1], mi[j + 2]);
        float n = min3f(hi[j], hi[j + 1], hi[j + 2]);
        o[j] = med3f(M, m, n);
    }

    float4 res;
    res.x = o[0]; res.y = o[1]; res.z = o[2]; res.w = o[3];
    *(float4*)(out + (size_t)p * IH * IW + (size_t)y * IW + x0) = res;
}

extern "C" void kernel_launch(void* const* d_in, const int* in_sizes, int n_in,
                              void* d_out, int out_size, void* d_ws, size_t ws_size,
                              hipStream_t stream) {
    const float* x = (const float*)d_in[0];
    float* out = (float*)d_out;
    // total threads: 48 planes * 512 rows * 128 groups = 3,145,728
    int total = NPLANES * IH * (IW / 4);
    int blocks = total / BLOCK;   // 12288
    median3x3_kernel<<<blocks, BLOCK, 0, stream>>>(x, out);
}

// Round 4
// 100.396 us; speedup vs baseline: 1.0552x; 1.0552x over previous
//
#include <hip/hip_runtime.h>

#define IW 512
#define IH 512
#define NPLANES 48            // 16 batch * 3 channels
#define BLOCK 256             // 4 waves = 4 rows per block

typedef float v4f __attribute__((ext_vector_type(4)));

__device__ __forceinline__ void sort3(float& a, float& b, float& c) {
    float t;
    t = fminf(a, b); b = fmaxf(a, b); a = t;
    t = fminf(b, c); c = fmaxf(b, c); b = t;
    t = fminf(a, b); b = fmaxf(a, b); a = t;
}
__device__ __forceinline__ float med3f(float a, float b, float c) {
    return __builtin_amdgcn_fmed3f(a, b, c);
}
__device__ __forceinline__ float max3f(float a, float b, float c) {
    return fmaxf(fmaxf(a, b), c);
}
__device__ __forceinline__ float min3f(float a, float b, float c) {
    return fminf(fminf(a, b), c);
}

// One wave (64 lanes) processes one full image row; each lane owns 8 columns.
__global__ __launch_bounds__(BLOCK) void median3x3_kernel(
    const float* __restrict__ x, float* __restrict__ out) {
    int tid  = blockIdx.x * BLOCK + threadIdx.x;
    int lane = threadIdx.x & 63;
    int w    = tid >> 6;            // global wave id = global row id
    int y    = w & (IH - 1);
    int p    = w >> 9;              // plane (512 rows = 2^9)
    int x0   = lane << 3;           // first of 8 columns owned by this lane

    const float* plane = x + (size_t)p * IH * IW;

    // reflect-pad rows (pad = 1)
    int ym = (y == 0)      ? 1      : y - 1;
    int yp = (y == IH - 1) ? IH - 2 : y + 1;

    // load 3 rows x 8 cols, fully coalesced float4 pairs
    float c[8][3];
    int rows[3] = {ym, y, yp};
#pragma unroll
    for (int i = 0; i < 3; i++) {
        const float* r = plane + (size_t)rows[i] * IW + x0;
        v4f a = *(const v4f*)(r);
        v4f b = *(const v4f*)(r + 4);
        c[0][i] = a.x; c[1][i] = a.y; c[2][i] = a.z; c[3][i] = a.w;
        c[4][i] = b.x; c[5][i] = b.y; c[6][i] = b.z; c[7][i] = b.w;
    }

    // vertical sort of each owned column -> (lo, mi, hi); exactly 1 sort3/column
    float lo[10], mi[10], hi[10];   // [0]=left halo, [1..8]=own, [9]=right halo
#pragma unroll
    for (int k = 0; k < 8; k++) {
        float a = c[k][0], b = c[k][1], d = c[k][2];
        sort3(a, b, d);
        lo[k + 1] = a; mi[k + 1] = b; hi[k + 1] = d;
    }

    // halo exchange of SORTED triples via wave shuffles
    // left halo = lane-1's col 7 ; lane 0 reflects to its own col index 1
    float Ll = __shfl_up(lo[8], 1, 64);
    float Lm = __shfl_up(mi[8], 1, 64);
    float Lh = __shfl_up(hi[8], 1, 64);
    // right halo = lane+1's col 0 ; lane 63 reflects to its own col 510 (local 6)
    float Rl = __shfl_down(lo[1], 1, 64);
    float Rm = __shfl_down(mi[1], 1, 64);
    float Rh = __shfl_down(hi[1], 1, 64);
    if (lane == 0)  { Ll = lo[2]; Lm = mi[2]; Lh = hi[2]; }  // reflect col -1 -> col 1
    if (lane == 63) { Rl = lo[7]; Rm = mi[7]; Rh = hi[7]; }  // reflect col 512 -> col 510
    lo[0] = Ll; mi[0] = Lm; hi[0] = Lh;
    lo[9] = Rl; mi[9] = Rm; hi[9] = Rh;

    // horizontal merge: median9 = med3(max3(lo), med3(mi), min3(hi))
    float o[8];
#pragma unroll
    for (int j = 0; j < 8; j++) {
        float M = max3f(lo[j], lo[j + 1], lo[j + 2]);
        float m = med3f(mi[j], mi[j + 1], mi[j + 2]);
        float n = min3f(hi[j], hi[j + 1], hi[j + 2]);
        o[j] = med3f(M, m, n);
    }

    float* dst = out + (size_t)p * IH * IW + (size_t)y * IW + x0;
    v4f r0 = {o[0], o[1], o[2], o[3]};
    v4f r1 = {o[4], o[5], o[6], o[7]};
    __builtin_nontemporal_store(r0, (v4f*)dst);
    __builtin_nontemporal_store(r1, (v4f*)(dst + 4));
}

extern "C" void kernel_launch(void* const* d_in, const int* in_sizes, int n_in,
                              void* d_out, int out_size, void* d_ws, size_t ws_size,
                              hipStream_t stream) {
    const float* x = (const float*)d_in[0];
    float* out = (float*)d_out;
    // waves = 48 planes * 512 rows = 24576 ; threads = 24576*64
    int total = NPLANES * IH * 64;
    int blocks = total / BLOCK;   // 6144
    median3x3_kernel<<<blocks, BLOCK, 0, stream>>>(x, out);
}